// Round 9
// baseline (2394.515 us; speedup 1.0000x reference)
//
#include <hip/hip_runtime.h>
#include <cstdint>
#include <cstddef>

#define BB 128    // batch
#define TT 80     // seq
#define EE 100    // emb dim
#define EP 128    // padded emb dim
#define UU 2048   // units
#define G3 6144   // 3*UU
#define PLANE (BB * UU)   // 262144 elements (one [batch][unit] plane)

typedef __bf16 bf16x8 __attribute__((ext_vector_type(8)));
typedef float f32x4 __attribute__((ext_vector_type(4)));
typedef int   i32x4 __attribute__((ext_vector_type(4)));

static __device__ __forceinline__ unsigned short f2bf(float x) {
  union { float f; unsigned int u; } a; a.f = x;
  unsigned int r = a.u + 0x7fffu + ((a.u >> 16) & 1u);  // RNE
  return (unsigned short)(r >> 16);
}

static __device__ __forceinline__ float sigf(float x) {
  return 1.f / (1.f + __expf(-x));
}
static __device__ __forceinline__ float tanhfast(float x) {
  return 1.f - 2.f / (__expf(2.f * x) + 1.f);
}

// Stage A of per-column absmax (R2 version: 2304 blocks, 64-row chunks,
// float4 coalesced, atomicMax on uint bits; ~48 us).
__global__ __launch_bounds__(256) void colmax_k(const float* __restrict__ s0,
                                                const float* __restrict__ s1,
                                                const float* __restrict__ s2,
                                                unsigned int* __restrict__ cmax) {
  int b = blockIdx.x;
  int cg = b % 24;           // column group (256 cols)
  int rc = (b / 24) & 31;    // row chunk (64 rows)
  int mat = b / 768;         // which matrix
  const float* src = (mat == 0) ? s0 : (mat == 1) ? s1 : s2;
  int fc = threadIdx.x & 63;   // float4 column within group
  int r0 = threadIdx.x >> 6;   // 0..3
  const char* base = (const char*)src
      + ((size_t)(rc * 64 + r0) * G3 + cg * 256 + fc * 4) * 4;
  f32x4 m = {0.f, 0.f, 0.f, 0.f};
#pragma unroll
  for (int k = 0; k < 16; ++k) {
    f32x4 v = *reinterpret_cast<const f32x4*>(base + (size_t)k * (4 * G3 * 4));
#pragma unroll
    for (int i = 0; i < 4; ++i) m[i] = fmaxf(m[i], fabsf(v[i]));
  }
  __shared__ f32x4 red[256];
  red[threadIdx.x] = m;
  __syncthreads();
  if (threadIdx.x < 64) {
    int t = threadIdx.x;
    f32x4 a = red[t], b2 = red[t + 64], c2 = red[t + 128], d2 = red[t + 192];
    unsigned int* out = cmax + mat * G3 + cg * 256 + t * 4;
#pragma unroll
    for (int i = 0; i < 4; ++i) {
      float mm = fmaxf(fmaxf(a[i], b2[i]), fmaxf(c2[i], d2[i]));
      atomicMax(out + i, __float_as_uint(mm));
    }
  }
}

// Stage B: colmax bits -> fscale = m/127^2 and qinv = 127/m (in place).
__global__ void colscale_fin_k(float* __restrict__ fs,
                               unsigned int* __restrict__ qinv) {
  int i = blockIdx.x * 256 + threadIdx.x;
  float m = __uint_as_float(qinv[i]);
  fs[i] = m * (1.f / 16129.f);
  reinterpret_cast<float*>(qinv)[i] = 127.f / m;
}

// fp32 (2048 x 6144) -> int8 MFMA-tiled (per-column scaled), all 3 matrices.
// lane L of chunk c holds B[k = c*64 + (L>>4)*16 + j][col = ct*16 + (L&15)].
__global__ __launch_bounds__(256) void convert_w_i8(const float* __restrict__ s0,
                                                    const float* __restrict__ s1,
                                                    const float* __restrict__ s2,
                                                    const float* __restrict__ qinv,
                                                    signed char* __restrict__ dst) {
  int mb = blockIdx.x / 3072;
  int tid = (blockIdx.x - mb * 3072) * 256 + threadIdx.x;   // 786432 groups/mat
  const float* src = (mb == 0) ? s0 : (mb == 1) ? s1 : s2;
  const float* qi_ = qinv + mb * G3;
  signed char* d_ = dst + (size_t)mb * 12582912;
  int gg = tid >> 18;
  int rem = tid & 262143;
  int ctc = rem >> 6;          // ct*32 + c
  int L = rem & 63;
  int ct = ctc >> 5, c = ctc & 31;
  int nl = L & 15, kq = L >> 4;
  int ocol = gg * 2048 + ct * 16 + nl;
  int kbase = c * 64 + kq * 16;
  float qi = qi_[ocol];
  union { signed char b[16]; int4 v; } o;
#pragma unroll
  for (int j = 0; j < 16; ++j) {
    int k = kbase + j;
    int q = (int)rintf(src[(size_t)k * G3 + ocol] * qi);
    o.b[j] = (signed char)q;
  }
  *reinterpret_cast<int4*>(d_ + (size_t)tid * 16) = o.v;
}

// fp32 (ksrc x 6144) -> bf16 MFMA-tiled layout (W0K only, K padded to 128).
__global__ void convert_w(const float* __restrict__ src, unsigned short* __restrict__ dst,
                          int ksrc, int kc_shift) {
  int tid = blockIdx.x * 256 + threadIdx.x;
  int nl = tid & 15;
  int kb = (tid >> 4) & 3;
  int kc_mask = (1 << kc_shift) - 1;
  int c  = (tid >> 6) & kc_mask;
  int ct = tid >> (6 + kc_shift);
  int col = ct * 16 + nl;
  int kbase = c * 32 + kb * 8;
  union { unsigned short u[8]; int4 v; } o;
#pragma unroll
  for (int j = 0; j < 8; ++j) {
    int k = kbase + j;
    float v = (k < ksrc) ? src[(size_t)k * G3 + col] : 0.f;
    o.u[j] = f2bf(v);
  }
  *reinterpret_cast<int4*>(dst + (size_t)tid * 8) = o.v;
}

// X[t][b][e] = bf16(emb[tokens[b][t]][e]), e padded to 128 with zeros.
__global__ void embed_k(const int* __restrict__ tokens, const float* __restrict__ emb,
                        unsigned short* __restrict__ X) {
  int idx = blockIdx.x * 256 + threadIdx.x;
  int e = idx & (EP - 1);
  int b = (idx >> 7) & (BB - 1);
  int t = idx >> 14;
  float v = 0.f;
  if (e < EE) {
    int tok = tokens[b * TT + t];
    v = emb[(size_t)tok * EE + e];
  }
  X[idx] = f2bf(v);
}

// Fused step dispatch d (0..81), v6: slot-rebalanced 2-stage pipeline.
// 256 blocks x 256 threads, LDS double-buffered weight windows, mt=2.
//   type A (blk<128), active d<80: computes h0(d). Slots (A-operand h0(d-1)
//     for ALL): {r0-z, r0-r, r0-h, k1-z, k1-r} + x_d@k0 input proj.
//     Epilogue: h0 gates -> H0F/H0Q3[d%3]; partial L1-input projections
//     gi_z(d-1), gi_r(d-1) (dequantized f32) -> GIZ/GIR[(d+1)&1].
//   type B (blk>=128), active 2<=d<82: finalizes h1(e), e=d-2. Slots:
//     {k1-h on h0(e), r1-z, r1-r, r1-h on h1(e-1)}; reads gi_z/gi_r(e) from
//     GIZ/GIR[d&1]; gates -> H1F/H1Q[d&1].
// Balance: A ~5.2 slot-equivalents, B ~4.3 (was 3.2 vs 6.2). Weight stream
// unchanged (each slot read once per step). Arithmetic identical to v5
// (gi routed through f32 planes is bit-exact).
// Buffers: H0Q3 mod-3 (A@d writes d%3, reads (d+2)%3; B reads (d+1)%3 —
// all distinct). H1Q parity (B writes d&1, reads (d+1)&1). Kernel boundaries
// give cross-XCD visibility.
__global__ __launch_bounds__(256) void step_fused(
    int d,
    const unsigned short* __restrict__ X,
    const unsigned short* __restrict__ W0K,
    const signed char* __restrict__ QW0R, const signed char* __restrict__ QW1K,
    const float* __restrict__ FS0R, const float* __restrict__ FS1K,
    const float* __restrict__ FS1R,
    const float* __restrict__ b0, const float* __restrict__ b1,
    float* __restrict__ H0F, float* __restrict__ H1F,
    signed char* __restrict__ H0Q3, signed char* __restrict__ H1Q,
    float* __restrict__ GIZ, float* __restrict__ GIR) {
  int blk = blockIdx.x;
  bool tA = blk < 128;
  if (tA) { if (d >= TT) return; }
  else    { if (d < 2 || d >= TT + 2) return; }
  int ct16 = tA ? blk : blk - 128;
  int lane = threadIdx.x & 63;
  int wave = threadIdx.x >> 6;   // 0..3, rows [wave*32, +32)
  int nl = lane & 15, kq = lane >> 4;
  int u = ct16 * 16 + nl;

  __shared__ unsigned char sbuf[40960];   // A: 2x20KB, B: 2x16KB

  if (tA) {
    // =========================== type A ===========================
    // preloads
    float fs0 = FS0R[u], fs1 = FS0R[UU + u], fs2 = FS0R[2 * UU + u];
    float fkz = FS1K[u], fkr = FS1K[UU + u];
    float bz  = b0[u] + b0[G3 + u];
    float br  = b0[UU + u] + b0[G3 + UU + u];
    float bih = b0[2 * UU + u];
    float bhh = b0[G3 + 2 * UU + u];
    float hold[2][4];
#pragma unroll
    for (int mt = 0; mt < 2; ++mt) {
      int m0 = wave * 32 + mt * 16 + kq * 4;
#pragma unroll
      for (int rr = 0; rr < 4; ++rr)
        hold[mt][rr] = H0F[(size_t)(m0 + rr) * UU + u];
    }

    const signed char* AqI = H0Q3 + (size_t)((d + 2) % 3) * PLANE;  // h0(d-1)
    const signed char* apI[2];
#pragma unroll
    for (int mt = 0; mt < 2; ++mt)
      apI[mt] = AqI + (size_t)(wave * 32 + mt * 16 + nl) * UU + kq * 16;

    // staging: 5 slots x 4 kc per 20 KB window; wslot = kcw*5 + s
    // slot bases: s<3 -> QW0R + s*4M ; s=3 -> QW1K + 0 ; s=4 -> QW1K + 4M
    int woff[5];
    const signed char* wbase[5];
    {
      int t = threadIdx.x;
#pragma unroll
      for (int i = 0; i < 5; ++i) {
        int ss = i * 256 + t;
        int wslot = ss >> 6, l16 = ss & 63;
        int s = wslot % 5, kcw = wslot / 5;
        const signed char* bp = (s < 3) ? (QW0R + (size_t)s * 4194304)
                                        : (QW1K + (size_t)(s - 3) * 4194304);
        wbase[i] = bp;
        woff[i] = (ct16 * 32 + kcw) * 1024 + l16 * 16;
      }
    }
    int soff0 = threadIdx.x * 16;
    {
      int4 v[5];
#pragma unroll
      for (int i = 0; i < 5; ++i)
        v[i] = *reinterpret_cast<const int4*>(wbase[i] + (size_t)woff[i]);
#pragma unroll
      for (int i = 0; i < 5; ++i)
        *reinterpret_cast<int4*>(&sbuf[soff0 + i * 4096]) = v[i];
    }
    __syncthreads();

    i32x4 acc[5][2];
#pragma unroll
    for (int s = 0; s < 5; ++s)
#pragma unroll
      for (int mt = 0; mt < 2; ++mt) acc[s][mt] = {0, 0, 0, 0};

    i32x4 aI[2], nI[2];
#pragma unroll
    for (int mt = 0; mt < 2; ++mt)
      aI[mt] = *reinterpret_cast<const i32x4*>(apI[mt]);

#pragma unroll
    for (int w = 0; w < 8; ++w) {
      int4 v[5];
      if (w < 7) {
#pragma unroll
        for (int i = 0; i < 5; ++i)
          v[i] = *reinterpret_cast<const int4*>(
              wbase[i] + (size_t)woff[i] + (w + 1) * 4096);
      }
#pragma unroll
      for (int kcw = 0; kcw < 4; ++kcw) {
        int kc = w * 4 + kcw;
        if (kc < 31) {
#pragma unroll
          for (int mt = 0; mt < 2; ++mt)
            nI[mt] = *reinterpret_cast<const i32x4*>(apI[mt] + (size_t)(kc + 1) * 64);
        }
#pragma unroll
        for (int s = 0; s < 5; ++s) {
          i32x4 bw = *reinterpret_cast<const i32x4*>(
              &sbuf[(w & 1) * 20480 + (kcw * 5 + s) * 1024 + lane * 16]);
#pragma unroll
          for (int mt = 0; mt < 2; ++mt)
            acc[s][mt] = __builtin_amdgcn_mfma_i32_16x16x64_i8(
                aI[mt], bw, acc[s][mt], 0, 0, 0);
        }
        if (kc < 31) {
#pragma unroll
          for (int mt = 0; mt < 2; ++mt) aI[mt] = nI[mt];
        }
      }
      if (w < 7) {
#pragma unroll
        for (int i = 0; i < 5; ++i)
          *reinterpret_cast<int4*>(&sbuf[((w + 1) & 1) * 20480 + soff0 + i * 4096]) = v[i];
        __syncthreads();
      }
    }

    // input projection x_d @ k0 (bf16, K=128 padded): iz, ir, ih
    f32x4 ai[2][3];
    {
      const unsigned short* wp = W0K + (size_t)ct16 * 2048 + (size_t)lane * 8;
#pragma unroll
      for (int mt = 0; mt < 2; ++mt) {
        const unsigned short* xp = X + (size_t)d * BB * EP
            + (size_t)(wave * 32 + mt * 16 + nl) * EP + kq * 8;
        f32x4 t0 = {0,0,0,0}, t1 = {0,0,0,0}, t2 = {0,0,0,0};
#pragma unroll
        for (int c = 0; c < 4; ++c) {
          bf16x8 a  = *reinterpret_cast<const bf16x8*>(xp + c * 32);
          bf16x8 w0 = *reinterpret_cast<const bf16x8*>(wp + (size_t)0 * 262144 + c * 512);
          bf16x8 w1 = *reinterpret_cast<const bf16x8*>(wp + (size_t)1 * 262144 + c * 512);
          bf16x8 w2 = *reinterpret_cast<const bf16x8*>(wp + (size_t)2 * 262144 + c * 512);
          t0 = __builtin_amdgcn_mfma_f32_16x16x32_bf16(a, w0, t0, 0, 0, 0);
          t1 = __builtin_amdgcn_mfma_f32_16x16x32_bf16(a, w1, t1, 0, 0, 0);
          t2 = __builtin_amdgcn_mfma_f32_16x16x32_bf16(a, w2, t2, 0, 0, 0);
        }
        ai[mt][0] = t0; ai[mt][1] = t1; ai[mt][2] = t2;
      }
    }

    // epilogue: h0(d) gates + gi_z/gi_r(d-1) plane stores
    signed char* H0Qw = H0Q3 + (size_t)(d % 3) * PLANE;
    float* GIZp = GIZ + (size_t)((d + 1) & 1) * PLANE;
    float* GIRp = GIR + (size_t)((d + 1) & 1) * PLANE;
#pragma unroll
    for (int mt = 0; mt < 2; ++mt) {
      int m0 = wave * 32 + mt * 16 + kq * 4;
#pragma unroll
      for (int rr = 0; rr < 4; ++rr) {
        size_t o = (size_t)(m0 + rr) * UU + u;
        float hz = (float)acc[0][mt][rr] * fs0;
        float hr = (float)acc[1][mt][rr] * fs1;
        float hh = (float)acc[2][mt][rr] * fs2 + bhh;
        float z    = sigf(ai[mt][0][rr] + hz + bz);
        float rg   = sigf(ai[mt][1][rr] + hr + br);
        float cand = tanhfast(ai[mt][2][rr] + bih + rg * hh);
        float hn = z * hold[mt][rr] + (1.f - z) * cand;
        H0F[o] = hn;
        H0Qw[o] = (signed char)(int)rintf(hn * 127.f);
        GIZp[o] = (float)acc[3][mt][rr] * fkz;
        GIRp[o] = (float)acc[4][mt][rr] * fkr;
      }
    }
  } else {
    // =========================== type B ===========================
    // finalizes h1(e), e = d-2
    float fkh = FS1K[2 * UU + u];
    float frz = FS1R[u], frr = FS1R[UU + u], frh = FS1R[2 * UU + u];
    float bz  = b1[u] + b1[G3 + u];
    float br  = b1[UU + u] + b1[G3 + UU + u];
    float bih = b1[2 * UU + u];
    float bhh = b1[G3 + 2 * UU + u];
    const float* GIZp = GIZ + (size_t)(d & 1) * PLANE;   // gi_z(e)
    const float* GIRp = GIR + (size_t)(d & 1) * PLANE;   // gi_r(e)
    float hold[2][4], giz[2][4], gir[2][4];
#pragma unroll
    for (int mt = 0; mt < 2; ++mt) {
      int m0 = wave * 32 + mt * 16 + kq * 4;
#pragma unroll
      for (int rr = 0; rr < 4; ++rr) {
        size_t o = (size_t)(m0 + rr) * UU + u;
        hold[mt][rr] = H1F[o];
        giz[mt][rr] = GIZp[o];
        gir[mt][rr] = GIRp[o];
      }
    }

    const signed char* AqK = H0Q3 + (size_t)((d + 1) % 3) * PLANE;  // h0(e)
    const signed char* AqH = H1Q + (size_t)((d + 1) & 1) * PLANE;   // h1(e-1)
    const signed char* apK[2];
    const signed char* apH[2];
#pragma unroll
    for (int mt = 0; mt < 2; ++mt) {
      int row = wave * 32 + mt * 16 + nl;
      apK[mt] = AqK + (size_t)row * UU + kq * 16;
      apH[mt] = AqH + (size_t)row * UU + kq * 16;
    }

    // staging: 4 slots x 4 kc per 16 KB window; wslot = kcw*4 + s
    // slot bases: s=0 -> QW1K + 2*4M (k1-h); s>=1 -> QW1R + (s-1)*4M
    const signed char* QW1R = QW1K + 12582912;
    int woff[4];
    const signed char* wbase[4];
    {
      int t = threadIdx.x;
#pragma unroll
      for (int i = 0; i < 4; ++i) {
        int ss = i * 256 + t;
        int wslot = ss >> 6, l16 = ss & 63;
        int s = wslot & 3, kcw = wslot >> 2;
        const signed char* bp = (s == 0) ? (QW1K + (size_t)2 * 4194304)
                                         : (QW1R + (size_t)(s - 1) * 4194304);
        wbase[i] = bp;
        woff[i] = (ct16 * 32 + kcw) * 1024 + l16 * 16;
      }
    }
    int soff0 = threadIdx.x * 16;
    {
      int4 v[4];
#pragma unroll
      for (int i = 0; i < 4; ++i)
        v[i] = *reinterpret_cast<const int4*>(wbase[i] + (size_t)woff[i]);
#pragma unroll
      for (int i = 0; i < 4; ++i)
        *reinterpret_cast<int4*>(&sbuf[soff0 + i * 4096]) = v[i];
    }
    __syncthreads();

    i32x4 acc[4][2];
#pragma unroll
    for (int s = 0; s < 4; ++s)
#pragma unroll
      for (int mt = 0; mt < 2; ++mt) acc[s][mt] = {0, 0, 0, 0};

    i32x4 aK[2], aH[2], nK[2], nH[2];
#pragma unroll
    for (int mt = 0; mt < 2; ++mt) {
      aK[mt] = *reinterpret_cast<const i32x4*>(apK[mt]);
      aH[mt] = *reinterpret_cast<const i32x4*>(apH[mt]);
    }

#pragma unroll
    for (int w = 0; w < 8; ++w) {
      int4 v[4];
      if (w < 7) {
#pragma unroll
        for (int i = 0; i < 4; ++i)
          v[i] = *reinterpret_cast<const int4*>(
              wbase[i] + (size_t)woff[i] + (w + 1) * 4096);
      }
#pragma unroll
      for (int kcw = 0; kcw < 4; ++kcw) {
        int kc = w * 4 + kcw;
        if (kc < 31) {
#pragma unroll
          for (int mt = 0; mt < 2; ++mt) {
            nK[mt] = *reinterpret_cast<const i32x4*>(apK[mt] + (size_t)(kc + 1) * 64);
            nH[mt] = *reinterpret_cast<const i32x4*>(apH[mt] + (size_t)(kc + 1) * 64);
          }
        }
#pragma unroll
        for (int s = 0; s < 4; ++s) {
          i32x4 bw = *reinterpret_cast<const i32x4*>(
              &sbuf[(w & 1) * 16384 + (kcw * 4 + s) * 1024 + lane * 16]);
#pragma unroll
          for (int mt = 0; mt < 2; ++mt)
            acc[s][mt] = __builtin_amdgcn_mfma_i32_16x16x64_i8(
                (s == 0) ? aK[mt] : aH[mt], bw, acc[s][mt], 0, 0, 0);
        }
        if (kc < 31) {
#pragma unroll
          for (int mt = 0; mt < 2; ++mt) { aK[mt] = nK[mt]; aH[mt] = nH[mt]; }
        }
      }
      if (w < 7) {
#pragma unroll
        for (int i = 0; i < 4; ++i)
          *reinterpret_cast<int4*>(&sbuf[((w + 1) & 1) * 16384 + soff0 + i * 4096]) = v[i];
        __syncthreads();
      }
    }

    // epilogue: h1(e) gates
    signed char* H1Qw = H1Q + (size_t)(d & 1) * PLANE;
#pragma unroll
    for (int mt = 0; mt < 2; ++mt) {
      int m0 = wave * 32 + mt * 16 + kq * 4;
#pragma unroll
      for (int rr = 0; rr < 4; ++rr) {
        size_t o = (size_t)(m0 + rr) * UU + u;
        float ihv = (float)acc[0][mt][rr] * fkh;
        float hz  = (float)acc[1][mt][rr] * frz;
        float hr  = (float)acc[2][mt][rr] * frr;
        float hhv = (float)acc[3][mt][rr] * frh + bhh;
        float z    = sigf(giz[mt][rr] + hz + bz);
        float rg   = sigf(gir[mt][rr] + hr + br);
        float cand = tanhfast(ihv + bih + rg * hhv);
        float hn = z * hold[mt][rr] + (1.f - z) * cand;
        H1F[o] = hn;
        H1Qw[o] = (signed char)(int)rintf(hn * 127.f);
      }
    }
  }
}

// logits = sigmoid(h1 @ wout + bout): 128 blocks x 64 threads, one row each.
__global__ void out_k(const float* __restrict__ h1, const float* __restrict__ wout,
                      const float* __restrict__ bout, float* __restrict__ out) {
  int row = blockIdx.x;
  int lane = threadIdx.x;
  float s = 0.f;
  for (int i = lane; i < UU; i += 64) s += h1[(size_t)row * UU + i] * wout[i];
#pragma unroll
  for (int off = 32; off > 0; off >>= 1) s += __shfl_down(s, off);
  if (lane == 0) out[row] = 1.f / (1.f + __expf(-(s + bout[0])));
}

extern "C" void kernel_launch(void* const* d_in, const int* in_sizes, int n_in,
                              void* d_out, int out_size, void* d_ws, size_t ws_size,
                              hipStream_t stream) {
  const int*   tokens = (const int*)  d_in[0];
  const float* emb    = (const float*)d_in[1];
  const float* k0     = (const float*)d_in[2];
  const float* r0     = (const float*)d_in[3];
  const float* b0     = (const float*)d_in[4];
  const float* k1     = (const float*)d_in[5];
  const float* r1     = (const float*)d_in[6];
  const float* b1     = (const float*)d_in[7];
  const float* wout   = (const float*)d_in[8];
  const float* bout   = (const float*)d_in[9];
  float* out = (float*)d_out;

  char* ws = (char*)d_ws;
  unsigned short* W0K = (unsigned short*)(ws + 0);           //  1.5 MB bf16 tiled
  signed char* QW0R   = (signed char*)(ws + 1572864);        // 12.6 MB int8 tiled
  signed char* QW1K   = (signed char*)(ws + 14155776);       // 12.6 MB
  signed char* QW1R   = (signed char*)(ws + 26738688);       // 12.6 MB (= QW1K + 12582912)
  float* FS0R         = (float*)(ws + 39321600);             // 24 KB dequant scales
  float* FS1K         = (float*)(ws + 39346176);
  float* FS1R         = (float*)(ws + 39370752);
  float* QI0R         = (float*)(ws + 39395328);             // 3 x 24 KB quant inv-scales
  unsigned short* X   = (unsigned short*)(ws + 39469056);    //  2.6 MB bf16
  float* H0F          = (float*)(ws + 42090496);             //  1 MB fp32 state
  float* H1F          = (float*)(ws + 43139072);             //  1 MB
  signed char* H0Q3   = (signed char*)(ws + 44187648);       //  3 x 256 KB int8 state (mod-3)
  signed char* H1Q    = (signed char*)(ws + 44974080);       //  2 x 256 KB (parity)
  float* GIZ          = (float*)(ws + 45498368);             //  2 x 1 MB gi_z planes
  float* GIR          = (float*)(ws + 47595520);             //  2 x 1 MB gi_r planes
  // total ws use: 49,692,672 bytes
  (void)QW1R;

  // zero state (H0F, H1F, H0Q3, H1Q contiguous): 3.25 MiB
  hipMemsetAsync(ws + 42090496, 0, 3407872, stream);
  // zero colmax accumulators (3 x 24 KB)
  hipMemsetAsync(ws + 39395328, 0, 73728, stream);

  // per-column absmax + scale finalize
  colmax_k<<<2304, 256, 0, stream>>>(r0, k1, r1, (unsigned int*)QI0R);
  colscale_fin_k<<<72, 256, 0, stream>>>(FS0R, (unsigned int*)QI0R);

  // int8 tiled conversion, all three matrices in one launch
  convert_w_i8<<<9216, 256, 0, stream>>>(r0, k1, r1, QI0R, QW0R);

  // L0 input-proj weights stay bf16 (tiny, K=128 padded)
  convert_w<<<384, 256, 0, stream>>>(k0, W0K, 100, 2);

  // embedding gather (time-major, padded)
  embed_k<<<5120, 256, 0, stream>>>(tokens, emb, X);

  // 82 fused step dispatches (2-stage pipeline): dispatch d computes h0(d)
  // (+ gi(d-1) partials) and finalizes h1(d-2).
  for (int d = 0; d <= TT + 1; ++d) {
    step_fused<<<256, 256, 0, stream>>>(d, X, W0K, QW0R, QW1K,
                                        FS0R, FS1K, FS1R, b0, b1,
                                        H0F, H1F, H0Q3, H1Q, GIZ, GIR);
  }

  out_k<<<128, 64, 0, stream>>>(H1F, wout, bout, out);
}

// Round 10
// 1945.352 us; speedup vs baseline: 1.2309x; 1.2309x over previous
//
#include <hip/hip_runtime.h>
#include <cstdint>
#include <cstddef>

#define BB 128    // batch
#define TT 80     // seq
#define EE 100    // emb dim
#define EP 128    // padded emb dim
#define UU 2048   // units
#define G3 6144   // 3*UU
#define PLANE (BB * UU)   // 262144 elements (one [batch][unit] plane)

typedef __bf16 bf16x8 __attribute__((ext_vector_type(8)));
typedef float f32x4 __attribute__((ext_vector_type(4)));
typedef int   i32x4 __attribute__((ext_vector_type(4)));

static __device__ __forceinline__ unsigned short f2bf(float x) {
  union { float f; unsigned int u; } a; a.f = x;
  unsigned int r = a.u + 0x7fffu + ((a.u >> 16) & 1u);  // RNE
  return (unsigned short)(r >> 16);
}

static __device__ __forceinline__ float sigf(float x) {
  return 1.f / (1.f + __expf(-x));
}
static __device__ __forceinline__ float tanhfast(float x) {
  return 1.f - 2.f / (__expf(2.f * x) + 1.f);
}

// Async global->LDS 16-byte copy. LDS dest = wave-uniform base + lane*16
// (hardware contract); global src is per-lane. Counted by vmcnt; the
// compiler's vmcnt(0)-before-s_barrier drains it.
static __device__ __forceinline__ void gload_lds16(const signed char* g,
                                                   unsigned char* l) {
  __builtin_amdgcn_global_load_lds(
      (const __attribute__((address_space(1))) void*)g,
      (__attribute__((address_space(3))) void*)l, 16, 0, 0);
}

// Stage A of per-column absmax (R2 version: 2304 blocks, 64-row chunks,
// float4 coalesced, atomicMax on uint bits; ~48 us).
__global__ __launch_bounds__(256) void colmax_k(const float* __restrict__ s0,
                                                const float* __restrict__ s1,
                                                const float* __restrict__ s2,
                                                unsigned int* __restrict__ cmax) {
  int b = blockIdx.x;
  int cg = b % 24;           // column group (256 cols)
  int rc = (b / 24) & 31;    // row chunk (64 rows)
  int mat = b / 768;         // which matrix
  const float* src = (mat == 0) ? s0 : (mat == 1) ? s1 : s2;
  int fc = threadIdx.x & 63;   // float4 column within group
  int r0 = threadIdx.x >> 6;   // 0..3
  const char* base = (const char*)src
      + ((size_t)(rc * 64 + r0) * G3 + cg * 256 + fc * 4) * 4;
  f32x4 m = {0.f, 0.f, 0.f, 0.f};
#pragma unroll
  for (int k = 0; k < 16; ++k) {
    f32x4 v = *reinterpret_cast<const f32x4*>(base + (size_t)k * (4 * G3 * 4));
#pragma unroll
    for (int i = 0; i < 4; ++i) m[i] = fmaxf(m[i], fabsf(v[i]));
  }
  __shared__ f32x4 red[256];
  red[threadIdx.x] = m;
  __syncthreads();
  if (threadIdx.x < 64) {
    int t = threadIdx.x;
    f32x4 a = red[t], b2 = red[t + 64], c2 = red[t + 128], d2 = red[t + 192];
    unsigned int* out = cmax + mat * G3 + cg * 256 + t * 4;
#pragma unroll
    for (int i = 0; i < 4; ++i) {
      float mm = fmaxf(fmaxf(a[i], b2[i]), fmaxf(c2[i], d2[i]));
      atomicMax(out + i, __float_as_uint(mm));
    }
  }
}

// Stage B: colmax bits -> fscale = m/127^2 and qinv = 127/m (in place).
__global__ void colscale_fin_k(float* __restrict__ fs,
                               unsigned int* __restrict__ qinv) {
  int i = blockIdx.x * 256 + threadIdx.x;
  float m = __uint_as_float(qinv[i]);
  fs[i] = m * (1.f / 16129.f);
  reinterpret_cast<float*>(qinv)[i] = 127.f / m;
}

// fp32 (2048 x 6144) -> int8 MFMA-tiled (per-column scaled), all 3 matrices.
// lane L of chunk c holds B[k = c*64 + (L>>4)*16 + j][col = ct*16 + (L&15)].
__global__ __launch_bounds__(256) void convert_w_i8(const float* __restrict__ s0,
                                                    const float* __restrict__ s1,
                                                    const float* __restrict__ s2,
                                                    const float* __restrict__ qinv,
                                                    signed char* __restrict__ dst) {
  int mb = blockIdx.x / 3072;
  int tid = (blockIdx.x - mb * 3072) * 256 + threadIdx.x;   // 786432 groups/mat
  const float* src = (mb == 0) ? s0 : (mb == 1) ? s1 : s2;
  const float* qi_ = qinv + mb * G3;
  signed char* d_ = dst + (size_t)mb * 12582912;
  int gg = tid >> 18;
  int rem = tid & 262143;
  int ctc = rem >> 6;          // ct*32 + c
  int L = rem & 63;
  int ct = ctc >> 5, c = ctc & 31;
  int nl = L & 15, kq = L >> 4;
  int ocol = gg * 2048 + ct * 16 + nl;
  int kbase = c * 64 + kq * 16;
  float qi = qi_[ocol];
  union { signed char b[16]; int4 v; } o;
#pragma unroll
  for (int j = 0; j < 16; ++j) {
    int k = kbase + j;
    int q = (int)rintf(src[(size_t)k * G3 + ocol] * qi);
    o.b[j] = (signed char)q;
  }
  *reinterpret_cast<int4*>(d_ + (size_t)tid * 16) = o.v;
}

// fp32 (ksrc x 6144) -> bf16 MFMA-tiled layout (W0K only, K padded to 128).
__global__ void convert_w(const float* __restrict__ src, unsigned short* __restrict__ dst,
                          int ksrc, int kc_shift) {
  int tid = blockIdx.x * 256 + threadIdx.x;
  int nl = tid & 15;
  int kb = (tid >> 4) & 3;
  int kc_mask = (1 << kc_shift) - 1;
  int c  = (tid >> 6) & kc_mask;
  int ct = tid >> (6 + kc_shift);
  int col = ct * 16 + nl;
  int kbase = c * 32 + kb * 8;
  union { unsigned short u[8]; int4 v; } o;
#pragma unroll
  for (int j = 0; j < 8; ++j) {
    int k = kbase + j;
    float v = (k < ksrc) ? src[(size_t)k * G3 + col] : 0.f;
    o.u[j] = f2bf(v);
  }
  *reinterpret_cast<int4*>(dst + (size_t)tid * 8) = o.v;
}

// X[t][b][e] = bf16(emb[tokens[b][t]][e]), e padded to 128 with zeros.
__global__ void embed_k(const int* __restrict__ tokens, const float* __restrict__ emb,
                        unsigned short* __restrict__ X) {
  int idx = blockIdx.x * 256 + threadIdx.x;
  int e = idx & (EP - 1);
  int b = (idx >> 7) & (BB - 1);
  int t = idx >> 14;
  float v = 0.f;
  if (e < EE) {
    int tok = tokens[b * TT + t];
    v = emb[(size_t)tok * EE + e];
  }
  X[idx] = f2bf(v);
}

// Fused step dispatch d (0..80), v7 = R5 + async weight staging.
// 256 blocks x 512 threads (8 waves, each owns 16 batch rows). Weight
// windows staged via global_load_lds width=16 (no VGPR round trip, no
// ds_writes): per (i, wave) LDS dest = i*8192 + wave*1024 + lane*16
// (wave-uniform base + lane*16, HW contract) and global src = slot base +
// lane*16. Double-buffered 24 KB windows; one barrier per window (2-phase):
// async loads into buf[w+1] are issued only after the barrier that ended
// all reads of that buffer; the barrier's vmcnt(0) drains the DMA before
// buf[w+1] is read.
//   blocks [0,128)  type A: h0(d): r0 GEMM (3 slots, K=2048 int8) +
//     x_d@k0 (K=128 bf16) + gates -> H0F/H0Q.
//   blocks [128,256) type B: h1(d-1): 6 slots {k1,r1} x 3 gates, K=2048
//     int8, A-operands h0(d-1), h1(d-2) + gates -> H1F/H1Q.
// Parity double-buffered quantized state: h(s) in buf[s&1]; readers use the
// previous-parity buffer; kernel boundaries give cross-XCD visibility.
__global__ __launch_bounds__(512) void step_fused(
    int d,
    const unsigned short* __restrict__ X,
    const unsigned short* __restrict__ W0K,
    const signed char* __restrict__ QW0R, const signed char* __restrict__ QW1K,
    const float* __restrict__ FS0R, const float* __restrict__ FS1K,
    const float* __restrict__ FS1R,
    const float* __restrict__ b0, const float* __restrict__ b1,
    float* __restrict__ H0F, float* __restrict__ H1F,
    signed char* __restrict__ H0Q, signed char* __restrict__ H1Q) {
  int blk = blockIdx.x;
  bool tA = blk < 128;
  if (tA) { if (d >= TT) return; }
  else    { if (d < 1)   return; }
  int ct16 = tA ? blk : blk - 128;
  int lane = threadIdx.x & 63;
  int wave = threadIdx.x >> 6;   // 0..7, owns rows [wave*16, +16)
  int nl = lane & 15, kq = lane >> 4;
  int u = ct16 * 16 + nl;
  int row = wave * 16 + nl;

  __shared__ unsigned char sbuf[2][24576];   // double-buffered weight windows

  const signed char* AqI = H0Q + (size_t)((d + 1) & 1) * PLANE;  // h0(d-1)
  const signed char* AqH = H1Q + (size_t)(d & 1) * PLANE;        // h1(d-2)
  const signed char* apI = AqI + (size_t)row * UU + kq * 16;
  const signed char* apH = AqH + (size_t)row * UU + kq * 16;

  // staging map (512 threads => 3 x 16 B per 24 KB window).
  // LDS byte = ss*16 (ss = i*512 + tid) = wslot*1024 + l16*16, l16 = lane.
  //  type A: wslot = kcw*3 + gg         (kcw 0..7, window = 8 K-chunks)
  //  type B: wslot = kcw*6 + mat*3 + gg (kcw 0..3, window = 4 K-chunks)
  // QW1R = QW1K + 12582912 by construction (mat folded into offset).
  const signed char* QWB = tA ? QW0R : QW1K;
  int woff[3];
  {
    int t = threadIdx.x;
#pragma unroll
    for (int i = 0; i < 3; ++i) {
      int ss = i * 512 + t;
      int wslot = ss >> 6, l16 = ss & 63;
      int off;
      if (tA) {
        int kcw = wslot / 3, gg = wslot - kcw * 3;
        off = gg * 4194304 + (ct16 * 32 + kcw) * 1024 + l16 * 16;
      } else {
        int kcw = wslot / 6, rem = wslot - kcw * 6;
        int mat = rem / 3, gg = rem - mat * 3;
        off = mat * 12582912 + gg * 4194304 + (ct16 * 32 + kcw) * 1024 + l16 * 16;
      }
      woff[i] = off;
    }
  }
  // prologue: async-stage window 0
  {
    unsigned char* lb = &sbuf[0][wave * 1024];
#pragma unroll
    for (int i = 0; i < 3; ++i)
      gload_lds16(QWB + (size_t)woff[i], lb + i * 8192);
  }
  __syncthreads();

  if (tA) {
    // ---- type A: 3 slots, 4 windows of 8 K-chunks ----
    i32x4 acc[3];
#pragma unroll
    for (int gg = 0; gg < 3; ++gg) acc[gg] = {0, 0, 0, 0};

    i32x4 aI = *reinterpret_cast<const i32x4*>(apI);
    i32x4 nI;

#pragma unroll
    for (int w = 0; w < 4; ++w) {
      if (w < 3) {
        unsigned char* lb = &sbuf[(w + 1) & 1][wave * 1024];
#pragma unroll
        for (int i = 0; i < 3; ++i)
          gload_lds16(QWB + (size_t)woff[i] + (size_t)(w + 1) * 8192,
                      lb + i * 8192);
      }
#pragma unroll
      for (int kcw = 0; kcw < 8; ++kcw) {
        int kc = w * 8 + kcw;
        if (kc < 31)
          nI = *reinterpret_cast<const i32x4*>(apI + (size_t)(kc + 1) * 64);
#pragma unroll
        for (int gg = 0; gg < 3; ++gg) {
          i32x4 bw = *reinterpret_cast<const i32x4*>(
              &sbuf[w & 1][(kcw * 3 + gg) * 1024 + lane * 16]);
          acc[gg] = __builtin_amdgcn_mfma_i32_16x16x64_i8(aI, bw, acc[gg], 0, 0, 0);
        }
        if (kc < 31) aI = nI;
      }
      if (w < 3) __syncthreads();
    }

    // input projection x_d @ k0 (bf16, K=128 padded): iz, ir, ih
    f32x4 ai0 = {0,0,0,0}, ai1 = {0,0,0,0}, ai2 = {0,0,0,0};
    {
      const unsigned short* wp = W0K + (size_t)ct16 * 2048 + (size_t)lane * 8;
      const unsigned short* xp = X + (size_t)d * BB * EP + (size_t)row * EP + kq * 8;
#pragma unroll
      for (int c = 0; c < 4; ++c) {
        bf16x8 a  = *reinterpret_cast<const bf16x8*>(xp + c * 32);
        bf16x8 w0 = *reinterpret_cast<const bf16x8*>(wp + (size_t)0 * 262144 + c * 512);
        bf16x8 w1 = *reinterpret_cast<const bf16x8*>(wp + (size_t)1 * 262144 + c * 512);
        bf16x8 w2 = *reinterpret_cast<const bf16x8*>(wp + (size_t)2 * 262144 + c * 512);
        ai0 = __builtin_amdgcn_mfma_f32_16x16x32_bf16(a, w0, ai0, 0, 0, 0);
        ai1 = __builtin_amdgcn_mfma_f32_16x16x32_bf16(a, w1, ai1, 0, 0, 0);
        ai2 = __builtin_amdgcn_mfma_f32_16x16x32_bf16(a, w2, ai2, 0, 0, 0);
      }
    }

    // gates + state update for h0(d)
    float fsz = FS0R[u], fsr = FS0R[UU + u], fsh = FS0R[2 * UU + u];
    float bz  = b0[u] + b0[G3 + u];
    float br  = b0[UU + u] + b0[G3 + UU + u];
    float bih = b0[2 * UU + u];
    float bhh = b0[G3 + 2 * UU + u];
    signed char* H0Qw = H0Q + (size_t)(d & 1) * PLANE;
    int m0 = wave * 16 + kq * 4;
#pragma unroll
    for (int rr = 0; rr < 4; ++rr) {
      float hz = (float)acc[0][rr] * fsz;
      float hr = (float)acc[1][rr] * fsr;
      float hh = (float)acc[2][rr] * fsh + bhh;
      float z    = sigf(ai0[rr] + hz + bz);
      float rg   = sigf(ai1[rr] + hr + br);
      float cand = tanhfast(ai2[rr] + bih + rg * hh);
      size_t o = (size_t)(m0 + rr) * UU + u;
      float hold = H0F[o];
      float hn = z * hold + (1.f - z) * cand;
      H0F[o] = hn;
      H0Qw[o] = (signed char)(int)rintf(hn * 127.f);
    }
  } else {
    // ---- type B: 6 slots (k1 x 3, r1 x 3), 8 windows of 4 K-chunks ----
    i32x4 acc[6];
#pragma unroll
    for (int s = 0; s < 6; ++s) acc[s] = {0, 0, 0, 0};

    i32x4 aI = *reinterpret_cast<const i32x4*>(apI);
    i32x4 aH = *reinterpret_cast<const i32x4*>(apH);
    i32x4 nI, nH;

#pragma unroll
    for (int w = 0; w < 8; ++w) {
      if (w < 7) {
        unsigned char* lb = &sbuf[(w + 1) & 1][wave * 1024];
#pragma unroll
        for (int i = 0; i < 3; ++i)
          gload_lds16(QWB + (size_t)woff[i] + (size_t)(w + 1) * 4096,
                      lb + i * 8192);
      }
#pragma unroll
      for (int kcw = 0; kcw < 4; ++kcw) {
        int kc = w * 4 + kcw;
        if (kc < 31) {
          nI = *reinterpret_cast<const i32x4*>(apI + (size_t)(kc + 1) * 64);
          nH = *reinterpret_cast<const i32x4*>(apH + (size_t)(kc + 1) * 64);
        }
#pragma unroll
        for (int s = 0; s < 6; ++s) {
          i32x4 bw = *reinterpret_cast<const i32x4*>(
              &sbuf[w & 1][(kcw * 6 + s) * 1024 + lane * 16]);
          acc[s] = __builtin_amdgcn_mfma_i32_16x16x64_i8(
              (s < 3) ? aI : aH, bw, acc[s], 0, 0, 0);
        }
        if (kc < 31) { aI = nI; aH = nH; }
      }
      if (w < 7) __syncthreads();
    }

    // gates + state update for h1(d-1)
    float fiz = FS1K[u], fir = FS1K[UU + u], fih = FS1K[2 * UU + u];
    float fhz = FS1R[u], fhr = FS1R[UU + u], fhh = FS1R[2 * UU + u];
    float bz  = b1[u] + b1[G3 + u];
    float br  = b1[UU + u] + b1[G3 + UU + u];
    float bih = b1[2 * UU + u];
    float bhh = b1[G3 + 2 * UU + u];
    signed char* H1Qw = H1Q + (size_t)((d + 1) & 1) * PLANE;
    int m0 = wave * 16 + kq * 4;
#pragma unroll
    for (int rr = 0; rr < 4; ++rr) {
      float iz  = (float)acc[0][rr] * fiz;
      float ir  = (float)acc[1][rr] * fir;
      float ihv = (float)acc[2][rr] * fih;
      float hz  = (float)acc[3][rr] * fhz;
      float hr  = (float)acc[4][rr] * fhr;
      float hhv = (float)acc[5][rr] * fhh + bhh;
      float z    = sigf(iz + hz + bz);
      float rg   = sigf(ir + hr + br);
      float cand = tanhfast(ihv + bih + rg * hhv);
      size_t o = (size_t)(m0 + rr) * UU + u;
      float hold = H1F[o];
      float hn = z * hold + (1.f - z) * cand;
      H1F[o] = hn;
      H1Qw[o] = (signed char)(int)rintf(hn * 127.f);
    }
  }
}

// logits = sigmoid(h1 @ wout + bout): 128 blocks x 64 threads, one row each.
__global__ void out_k(const float* __restrict__ h1, const float* __restrict__ wout,
                      const float* __restrict__ bout, float* __restrict__ out) {
  int row = blockIdx.x;
  int lane = threadIdx.x;
  float s = 0.f;
  for (int i = lane; i < UU; i += 64) s += h1[(size_t)row * UU + i] * wout[i];
#pragma unroll
  for (int off = 32; off > 0; off >>= 1) s += __shfl_down(s, off);
  if (lane == 0) out[row] = 1.f / (1.f + __expf(-(s + bout[0])));
}

extern "C" void kernel_launch(void* const* d_in, const int* in_sizes, int n_in,
                              void* d_out, int out_size, void* d_ws, size_t ws_size,
                              hipStream_t stream) {
  const int*   tokens = (const int*)  d_in[0];
  const float* emb    = (const float*)d_in[1];
  const float* k0     = (const float*)d_in[2];
  const float* r0     = (const float*)d_in[3];
  const float* b0     = (const float*)d_in[4];
  const float* k1     = (const float*)d_in[5];
  const float* r1     = (const float*)d_in[6];
  const float* b1     = (const float*)d_in[7];
  const float* wout   = (const float*)d_in[8];
  const float* bout   = (const float*)d_in[9];
  float* out = (float*)d_out;

  char* ws = (char*)d_ws;
  unsigned short* W0K = (unsigned short*)(ws + 0);           //  1.5 MB bf16 tiled
  signed char* QW0R   = (signed char*)(ws + 1572864);        // 12.6 MB int8 tiled
  signed char* QW1K   = (signed char*)(ws + 14155776);       // 12.6 MB
  signed char* QW1R   = (signed char*)(ws + 26738688);       // 12.6 MB (= QW1K + 12582912)
  float* FS0R         = (float*)(ws + 39321600);             // 24 KB dequant scales
  float* FS1K         = (float*)(ws + 39346176);
  float* FS1R         = (float*)(ws + 39370752);
  float* QI0R         = (float*)(ws + 39395328);             // 3 x 24 KB quant inv-scales
  unsigned short* X   = (unsigned short*)(ws + 39469056);    //  2.6 MB bf16
  float* H0F          = (float*)(ws + 42090496);             //  1 MB fp32 state
  float* H1F          = (float*)(ws + 43139072);             //  1 MB
  signed char* H0Q    = (signed char*)(ws + 44187648);       //  2 x 256 KB int8 state (parity)
  signed char* H1Q    = (signed char*)(ws + 44711936);       //  2 x 256 KB
  // total ws use: 45,236,224 bytes
  (void)QW1R;

  // zero state (H0F, H1F, H0Q[2], H1Q[2] contiguous): 3 MiB
  hipMemsetAsync(ws + 42090496, 0, 3145728, stream);
  // zero colmax accumulators (3 x 24 KB)
  hipMemsetAsync(ws + 39395328, 0, 73728, stream);

  // per-column absmax + scale finalize
  colmax_k<<<2304, 256, 0, stream>>>(r0, k1, r1, (unsigned int*)QI0R);
  colscale_fin_k<<<72, 256, 0, stream>>>(FS0R, (unsigned int*)QI0R);

  // int8 tiled conversion, all three matrices in one launch
  convert_w_i8<<<9216, 256, 0, stream>>>(r0, k1, r1, QI0R, QW0R);

  // L0 input-proj weights stay bf16 (tiny, K=128 padded)
  convert_w<<<384, 256, 0, stream>>>(k0, W0K, 100, 2);

  // embedding gather (time-major, padded)
  embed_k<<<5120, 256, 0, stream>>>(tokens, emb, X);

  // 81 fused step dispatches: d computes h0(d) and h1(d-1) in one kernel
  for (int d = 0; d <= TT; ++d) {
    step_fused<<<256, 512, 0, stream>>>(d, X, W0K, QW0R, QW1K,
                                        FS0R, FS1K, FS1R, b0, b1,
                                        H0F, H1F, H0Q, H1Q);
  }

  out_k<<<128, 64, 0, stream>>>(H1F, wout, bout, out);
}